// Round 2
// baseline (4196.851 us; speedup 1.0000x reference)
//
#include <hip/hip_runtime.h>
#include <hip/hip_bf16.h>

// ---------- helpers ----------
static __device__ __forceinline__ float ldf(const float* p, size_t i) { return p[i]; }
static __device__ __forceinline__ float ldf(const __hip_bfloat16* p, size_t i) { return __bfloat162float(p[i]); }
static __device__ __forceinline__ void stf(float* p, size_t i, float v) { p[i] = v; }
static __device__ __forceinline__ void stf(__hip_bfloat16* p, size_t i, float v) { p[i] = __float2bfloat16(v); }

// ---------- LN row stats: mean + rstd per token row ----------
__global__ void ln_stats_kernel(const float* __restrict__ x, float* __restrict__ stats, int C) {
  int row = blockIdx.x;
  int lane = threadIdx.x;               // 64 threads = 1 wave
  const float* p = x + (size_t)row * C;
  float s = 0.f, ss = 0.f;
  for (int k = lane; k < C; k += 64) { float v = p[k]; s += v; ss += v * v; }
  for (int o = 32; o > 0; o >>= 1) { s += __shfl_down(s, o); ss += __shfl_down(ss, o); }
  if (lane == 0) {
    float m = s / C;
    float var = ss / C - m * m;
    stats[2 * row]     = m;
    stats[2 * row + 1] = rsqrtf(var + 1e-5f);
  }
}

// ---------- generic 64x64x16 tiled fp32 GEMM ----------
// C[M,N] = epilogue(A'[M,K] @ B[K,N] + bias), A' = optional layernorm of A rows.
// EPI: 0 = none, 1 = +res, 2 = exact GELU
// Assumes M%64==0, N%64==0, K%16==0 (true for all calls here).
template <typename TA, typename TO, bool LN, int EPI>
__global__ __launch_bounds__(256) void gemm64_kernel(
    const TA* __restrict__ A, const float* __restrict__ B, const float* __restrict__ bias,
    const float* __restrict__ stats, const float* __restrict__ lng, const float* __restrict__ lnb,
    const float* __restrict__ res, TO* __restrict__ Cout,
    int M, int N, int K) {
  __shared__ float sA[16][65];   // [k][m]
  __shared__ float sB[16][65];   // [k][n]
  const int bm = blockIdx.y * 64;
  const int bn = blockIdx.x * 64;
  const int t  = threadIdx.x;
  const int ty = t >> 4, tx = t & 15;      // compute map: rows ty*4.., cols tx*4..
  float acc[4][4] = {};

  for (int k0 = 0; k0 < K; k0 += 16) {
    // load A tile 64x16 (as sA[k][m])
    {
      const int lk = t & 15, lm0 = t >> 4;
      const int kk = k0 + lk;
#pragma unroll
      for (int s = 0; s < 4; ++s) {
        const int mrel = lm0 + s * 16;
        const size_t m = (size_t)(bm + mrel);
        float v = ldf(A, m * K + kk);
        if (LN) v = (v - stats[2 * m]) * stats[2 * m + 1] * lng[kk] + lnb[kk];
        sA[lk][mrel] = v;
      }
    }
    // load B tile 16x64 (as sB[k][n])
    {
      const int ln_ = t & 63, lk0 = t >> 6;
#pragma unroll
      for (int s = 0; s < 4; ++s) {
        const int kk = k0 + lk0 + s * 4;
        sB[lk0 + s * 4][ln_] = B[(size_t)kk * N + bn + ln_];
      }
    }
    __syncthreads();
#pragma unroll
    for (int kk = 0; kk < 16; ++kk) {
      float a[4], b[4];
#pragma unroll
      for (int i = 0; i < 4; ++i) a[i] = sA[kk][ty * 4 + i];
#pragma unroll
      for (int j = 0; j < 4; ++j) b[j] = sB[kk][tx * 4 + j];
#pragma unroll
      for (int i = 0; i < 4; ++i)
#pragma unroll
        for (int j = 0; j < 4; ++j) acc[i][j] += a[i] * b[j];
    }
    __syncthreads();
  }

#pragma unroll
  for (int i = 0; i < 4; ++i) {
    const size_t m = (size_t)(bm + ty * 4 + i);
#pragma unroll
    for (int j = 0; j < 4; ++j) {
      const int n = bn + tx * 4 + j;
      float v = acc[i][j] + bias[n];
      if (EPI == 1) v += res[m * N + n];
      if (EPI == 2) v = 0.5f * v * (1.0f + erff(v * 0.70710678118654752f));
      stf(Cout, m * N + n, v);
    }
  }
}

// ---------- windowed attention, one block per (window, head) ----------
__global__ __launch_bounds__(256) void attn_kernel(
    const float* __restrict__ qkv, const float* __restrict__ biases, float* __restrict__ o) {
  __shared__ float sQ[49][32], sK[49][32], sV[49][32];
  __shared__ float sS[49][49];
  const int wid  = blockIdx.x / 18;  // 0..511
  const int head = blockIdx.x % 18;
  const int b  = wid >> 4;
  const int wi = wid & 15;
  const int wh = wi >> 2, wwc = wi & 3;
  const int tid = threadIdx.x;

  // load q,k,v for 49 tokens
  for (int idx = tid; idx < 49 * 96; idx += 256) {
    const int tkn = idx / 96, e = idx - tkn * 96;
    const int r = tkn / 7, cc = tkn - r * 7;
    const size_t row = (size_t)b * 784 + (size_t)((wh * 7 + r) * 28 + (wwc * 7 + cc));
    const float v = qkv[row * 1728 + head * 96 + e];
    if (e < 32)       sQ[tkn][e]      = v;
    else if (e < 64)  sK[tkn][e - 32] = v;
    else              sV[tkn][e - 64] = v;
  }
  __syncthreads();

  const float scale = 0.17677669529663687f;  // 32^-0.5
  for (int idx = tid; idx < 49 * 49; idx += 256) {
    const int i = idx / 49, j = idx - i * 49;
    float acc = 0.f;
#pragma unroll
    for (int d = 0; d < 32; ++d) acc += sQ[i][d] * sK[j][d];
    const int ri = i / 7, ci = i - ri * 7, rj = j / 7, cj = j - rj * 7;
    const float bia = biases[head * 49 + abs(ri - rj) * 7 + abs(ci - cj)];
    sS[i][j] = acc * scale + bia;
  }
  __syncthreads();

  if (tid < 49) {
    float m = -1e30f;
    for (int j = 0; j < 49; ++j) m = fmaxf(m, sS[tid][j]);
    float sum = 0.f;
    for (int j = 0; j < 49; ++j) { float e = expf(sS[tid][j] - m); sS[tid][j] = e; sum += e; }
    const float inv = 1.f / sum;
    for (int j = 0; j < 49; ++j) sS[tid][j] *= inv;
  }
  __syncthreads();

  for (int idx = tid; idx < 49 * 32; idx += 256) {
    const int i = idx / 32, d = idx - i * 32;
    float acc = 0.f;
    for (int j = 0; j < 49; ++j) acc += sS[i][j] * sV[j][d];
    const int r = i / 7, cc = i - r * 7;
    const size_t row = (size_t)b * 784 + (size_t)((wh * 7 + r) * 28 + (wwc * 7 + cc));
    o[row * 576 + head * 32 + d] = acc;
  }
}

// ---------- depthwise 3x3 conv + BN (channel-last layout) ----------
__global__ void conv_bn_kernel(const float* __restrict__ x1, const float* __restrict__ w,
                               const float* __restrict__ bng, const float* __restrict__ bnb,
                               const float* __restrict__ bnm, const float* __restrict__ bnv,
                               float* __restrict__ x2) {
  const size_t total = (size_t)32 * 784 * 576;
  const size_t idx = (size_t)blockIdx.x * 256 + threadIdx.x;
  if (idx >= total) return;
  const int c = (int)(idx % 576);
  const size_t p = idx / 576;
  const int pix = (int)(p % 784);
  const int b = (int)(p / 784);
  const int i = pix / 28, j = pix % 28;
  float acc = 0.f;
#pragma unroll
  for (int dh = -1; dh <= 1; ++dh) {
#pragma unroll
    for (int dw = -1; dw <= 1; ++dw) {
      const int ii = i + dh, jj = j + dw;
      if (ii >= 0 && ii < 28 && jj >= 0 && jj < 28)
        acc += x1[((size_t)b * 784 + ii * 28 + jj) * 576 + c] * w[c * 9 + (dh + 1) * 3 + (dw + 1)];
    }
  }
  const float inv = rsqrtf(bnv[c] + 1e-5f);
  x2[idx] = (acc - bnm[c]) * (inv * bng[c]) + bnb[c];
}

// ---------- launch ----------
extern "C" void kernel_launch(void* const* d_in, const int* in_sizes, int n_in,
                              void* d_out, int out_size, void* d_ws, size_t ws_size,
                              hipStream_t stream) {
  (void)in_sizes; (void)n_in; (void)out_size; (void)ws_size;
  const float* x      = (const float*)d_in[0];
  const float* ln1g   = (const float*)d_in[1];
  const float* ln1b   = (const float*)d_in[2];
  const float* qkv_w  = (const float*)d_in[3];
  const float* qkv_b  = (const float*)d_in[4];
  const float* biases = (const float*)d_in[5];
  const float* proj_w = (const float*)d_in[6];
  const float* proj_b = (const float*)d_in[7];
  const float* conv_w = (const float*)d_in[8];
  const float* bng    = (const float*)d_in[9];
  const float* bnb    = (const float*)d_in[10];
  const float* bnm    = (const float*)d_in[11];
  const float* bnv    = (const float*)d_in[12];
  const float* ln2g   = (const float*)d_in[13];
  const float* ln2b   = (const float*)d_in[14];
  const float* fc1_w  = (const float*)d_in[15];
  const float* fc1_b  = (const float*)d_in[16];
  const float* fc2_w  = (const float*)d_in[17];
  const float* fc2_b  = (const float*)d_in[18];
  float* out = (float*)d_out;

  const size_t M = 25088;  // 32 * 784 tokens
  char* ws = (char*)d_ws;
  // workspace layout (total ~221 MiB):
  //   [0, 401408)                      : stats1 (2*M f32) + stats2 (2*M f32)
  //   regQ = [401408, +173408256)      : qkv f32 (M x 1728); reused: x1 f32 (M x 576); reused: hm bf16 (M x 2304)
  //   regO = [.., +57802752)           : o f32 (M x 576); reused: x2 f32 (M x 576)
  float* stats1 = (float*)ws;
  float* stats2 = stats1 + 2 * M;
  char* regQ = ws + 401408;
  char* regO = regQ + 173408256;
  float* qkv  = (float*)regQ;
  float* obuf = (float*)regO;
  float* x1   = (float*)regQ;
  float* x2   = (float*)regO;
  __hip_bfloat16* hm = (__hip_bfloat16*)regQ;

  // 1. LN1 stats on x
  ln_stats_kernel<<<(int)M, 64, 0, stream>>>(x, stats1, 576);
  // 2. qkv = LN1(x) @ qkv_w + qkv_b
  gemm64_kernel<float, float, true, 0><<<dim3(1728 / 64, M / 64), 256, 0, stream>>>(
      x, qkv_w, qkv_b, stats1, ln1g, ln1b, nullptr, qkv, M, 1728, 576);
  // 3. windowed attention per (window, head)
  attn_kernel<<<512 * 18, 256, 0, stream>>>(qkv, biases, obuf);
  // 4. x1 = x + (o @ proj_w + proj_b)
  gemm64_kernel<float, float, false, 1><<<dim3(576 / 64, M / 64), 256, 0, stream>>>(
      obuf, proj_w, proj_b, nullptr, nullptr, nullptr, x, x1, M, 576, 576);
  // 5. x2 = BN(dwconv3x3(x1))
  conv_bn_kernel<<<(32 * 784 * 576 + 255) / 256, 256, 0, stream>>>(x1, conv_w, bng, bnb, bnm, bnv, x2);
  // 6. LN2 stats on x2
  ln_stats_kernel<<<(int)M, 64, 0, stream>>>(x2, stats2, 576);
  // 7. hm = gelu(LN2(x2) @ fc1_w + fc1_b)   (stored bf16)
  gemm64_kernel<float, __hip_bfloat16, true, 2><<<dim3(2304 / 64, M / 64), 256, 0, stream>>>(
      x2, fc1_w, fc1_b, stats2, ln2g, ln2b, nullptr, hm, M, 2304, 576);
  // 8. out = x2 + (hm @ fc2_w + fc2_b)
  gemm64_kernel<__hip_bfloat16, float, false, 1><<<dim3(576 / 64, M / 64), 256, 0, stream>>>(
      hm, fc2_w, fc2_b, nullptr, nullptr, nullptr, x2, out, M, 576, 2304);
}

// Round 5
// 894.343 us; speedup vs baseline: 4.6927x; 4.6927x over previous
//
#include <hip/hip_runtime.h>
#include <hip/hip_bf16.h>

typedef __attribute__((ext_vector_type(8))) short bf16x8;
typedef __attribute__((ext_vector_type(4))) float f32x4;

static __device__ __forceinline__ void stf(float* p, size_t i, float v) { p[i] = v; }
static __device__ __forceinline__ void stf(__hip_bfloat16* p, size_t i, float v) { p[i] = __float2bfloat16(v); }

static __device__ __forceinline__ void gload_lds16(const void* g, void* l) {
  __builtin_amdgcn_global_load_lds((const __attribute__((address_space(1))) void*)g,
                                   (__attribute__((address_space(3))) void*)l, 16, 0, 0);
}

// ---------- weight transpose + bf16 convert: W[K][N] f32 -> WT[N][K] bf16 ----------
__global__ void wt_kernel(const float* __restrict__ W, __hip_bfloat16* __restrict__ WT, int K, int N) {
  __shared__ float tile[32][33];
  const int kb = blockIdx.y * 32, nb = blockIdx.x * 32;
  const int tx = threadIdx.x & 31, ty = threadIdx.x >> 5;  // 256 thr: ty 0..7
#pragma unroll
  for (int i = 0; i < 4; ++i)
    tile[ty + i * 8][tx] = W[(size_t)(kb + ty + i * 8) * N + nb + tx];
  __syncthreads();
#pragma unroll
  for (int i = 0; i < 4; ++i)
    WT[(size_t)(nb + ty + i * 8) * K + kb + tx] = __float2bfloat16(tile[tx][ty + i * 8]);
}

// ---------- fused LN -> bf16: one wave per 576-elem row ----------
__global__ void ln_bf16_kernel(const float* __restrict__ x, const float* __restrict__ g,
                               const float* __restrict__ b, __hip_bfloat16* __restrict__ y) {
  const int row = blockIdx.x * 4 + (threadIdx.x >> 6);
  const int lane = threadIdx.x & 63;
  const float* p = x + (size_t)row * 576;
  float vals[9];
  float s = 0.f, ss = 0.f;
#pragma unroll
  for (int i = 0; i < 9; ++i) {
    float v = p[lane + i * 64];
    vals[i] = v; s += v; ss += v * v;
  }
#pragma unroll
  for (int o = 32; o; o >>= 1) { s += __shfl_down(s, o); ss += __shfl_down(ss, o); }
  s = __shfl(s, 0); ss = __shfl(ss, 0);
  const float m = s * (1.f / 576.f);
  const float rstd = rsqrtf(ss * (1.f / 576.f) - m * m + 1e-5f);
  __hip_bfloat16* q = y + (size_t)row * 576;
#pragma unroll
  for (int i = 0; i < 9; ++i) {
    const int c = lane + i * 64;
    q[c] = __float2bfloat16((vals[i] - m) * rstd * g[c] + b[c]);
  }
}

// ---------- MFMA GEMM: C[M,N] = epi(A[M,K] @ BT[N,K]^T + bias) ----------
// tile 128x64, BK=64, 4 waves (2x2), mfma_f32_16x16x32_bf16, gload_lds + XOR swizzle.
// EPI: 0 none, 1 +res, 2 exact GELU
template <int EPI, typename TO>
__global__ __launch_bounds__(256) void gemm_bt(
    const __hip_bfloat16* __restrict__ A, const __hip_bfloat16* __restrict__ BT,
    const float* __restrict__ bias, const float* __restrict__ res, TO* __restrict__ C,
    int M, int N, int K) {
  __shared__ __hip_bfloat16 sA[2][128 * 64];
  __shared__ __hip_bfloat16 sB[2][64 * 64];
  const int t = threadIdx.x;
  const int lane = t & 63;
  const int w = t >> 6;
  const int bm = blockIdx.y * 128, bn = blockIdx.x * 64;
  const int wm = (w >> 1) * 64, wn = (w & 1) * 32;
  const int l15 = lane & 15, l4 = lane >> 4;

  f32x4 acc[4][2];
#pragma unroll
  for (int mi = 0; mi < 4; ++mi)
#pragma unroll
    for (int ni = 0; ni < 2; ++ni) acc[mi][ni] = (f32x4){0.f, 0.f, 0.f, 0.f};

  const int wave_base = t & ~63;  // wave-uniform

  auto stage = [&](int buf, int k0) {
    // A tile: 128 rows x 64 k, 1024 slots of 8 bf16
#pragma unroll
    for (int i = 0; i < 4; ++i) {
      const int slot = i * 256 + t;
      const int row = slot >> 3, kst = slot & 7;
      const int ksrc = kst ^ (row & 7);
      const __hip_bfloat16* g = A + (size_t)(bm + row) * K + k0 + ksrc * 8;
      gload_lds16(g, sA[buf] + (i * 256 + wave_base) * 8);
    }
    // B tile: 64 rows x 64 k, 512 slots
#pragma unroll
    for (int i = 0; i < 2; ++i) {
      const int slot = i * 256 + t;
      const int row = slot >> 3, kst = slot & 7;
      const int ksrc = kst ^ (row & 7);
      const __hip_bfloat16* g = BT + (size_t)(bn + row) * K + k0 + ksrc * 8;
      gload_lds16(g, sB[buf] + (i * 256 + wave_base) * 8);
    }
  };

  auto compute = [&](int buf) {
    const __hip_bfloat16* pA = sA[buf];
    const __hip_bfloat16* pB = sB[buf];
#pragma unroll
    for (int kb = 0; kb < 2; ++kb) {
      bf16x8 a[4], b[2];
      const int kblk = kb * 4 + l4;
#pragma unroll
      for (int mi = 0; mi < 4; ++mi) {
        const int row = wm + mi * 16 + l15;
        a[mi] = *(const bf16x8*)(pA + row * 64 + ((kblk ^ (row & 7)) * 8));
      }
#pragma unroll
      for (int ni = 0; ni < 2; ++ni) {
        const int row = wn + ni * 16 + l15;
        b[ni] = *(const bf16x8*)(pB + row * 64 + ((kblk ^ (row & 7)) * 8));
      }
#pragma unroll
      for (int mi = 0; mi < 4; ++mi)
#pragma unroll
        for (int ni = 0; ni < 2; ++ni)
          acc[mi][ni] = __builtin_amdgcn_mfma_f32_16x16x32_bf16(a[mi], b[ni], acc[mi][ni], 0, 0, 0);
    }
  };

  const int nt = K >> 6;
  stage(0, 0);
  __syncthreads();
  int cur = 0;
  for (int tt = 0; tt < nt - 1; ++tt) {
    stage(cur ^ 1, (tt + 1) << 6);
    compute(cur);
    __syncthreads();
    cur ^= 1;
  }
  compute(cur);

  // epilogue: C/D layout col=lane&15, row=(lane>>4)*4+reg
#pragma unroll
  for (int mi = 0; mi < 4; ++mi) {
    const int mrow = bm + wm + mi * 16 + l4 * 4;
#pragma unroll
    for (int ni = 0; ni < 2; ++ni) {
      const int col = bn + wn + ni * 16 + l15;
      const float bv = bias[col];
#pragma unroll
      for (int r = 0; r < 4; ++r) {
        const size_t idx = (size_t)(mrow + r) * N + col;
        float v = acc[mi][ni][r] + bv;
        if (EPI == 1) v += res[idx];
        if (EPI == 2) v = 0.5f * v * (1.0f + erff(v * 0.70710678118654752f));
        stf(C, idx, v);
      }
    }
  }
}

// ---------- windowed attention, one block per (window, head), bf16 in/out ----------
__global__ __launch_bounds__(256) void attn_kernel(
    const __hip_bfloat16* __restrict__ qkv, const float* __restrict__ biases,
    __hip_bfloat16* __restrict__ o) {
  __shared__ float sQ[49][32], sK[49][32], sV[49][32];
  __shared__ float sS[49][49];
  const int wid  = blockIdx.x / 18;
  const int head = blockIdx.x % 18;
  const int b  = wid >> 4;
  const int wi = wid & 15;
  const int wh = wi >> 2, wwc = wi & 3;
  const int tid = threadIdx.x;

  for (int idx = tid; idx < 49 * 96; idx += 256) {
    const int tkn = idx / 96, e = idx - tkn * 96;
    const int r = tkn / 7, cc = tkn - r * 7;
    const size_t row = (size_t)b * 784 + (size_t)((wh * 7 + r) * 28 + (wwc * 7 + cc));
    const float v = __bfloat162float(qkv[row * 1728 + head * 96 + e]);
    if (e < 32)       sQ[tkn][e]      = v;
    else if (e < 64)  sK[tkn][e - 32] = v;
    else              sV[tkn][e - 64] = v;
  }
  __syncthreads();

  const float scale = 0.17677669529663687f;
  for (int idx = tid; idx < 49 * 49; idx += 256) {
    const int i = idx / 49, j = idx - i * 49;
    float acc = 0.f;
#pragma unroll
    for (int d = 0; d < 32; ++d) acc += sQ[i][d] * sK[j][d];
    const int ri = i / 7, ci = i - ri * 7, rj = j / 7, cj = j - rj * 7;
    sS[i][j] = acc * scale + biases[head * 49 + abs(ri - rj) * 7 + abs(ci - cj)];
  }
  __syncthreads();

  if (tid < 49) {
    float m = -1e30f;
    for (int j = 0; j < 49; ++j) m = fmaxf(m, sS[tid][j]);
    float sum = 0.f;
    for (int j = 0; j < 49; ++j) { float e = expf(sS[tid][j] - m); sS[tid][j] = e; sum += e; }
    const float inv = 1.f / sum;
    for (int j = 0; j < 49; ++j) sS[tid][j] *= inv;
  }
  __syncthreads();

  for (int idx = tid; idx < 49 * 32; idx += 256) {
    const int i = idx / 32, d = idx - i * 32;
    float acc = 0.f;
    for (int j = 0; j < 49; ++j) acc += sS[i][j] * sV[j][d];
    const int r = i / 7, cc = i - r * 7;
    const size_t row = (size_t)b * 784 + (size_t)((wh * 7 + r) * 28 + (wwc * 7 + cc));
    o[row * 576 + head * 32 + d] = __float2bfloat16(acc);
  }
}

// ---------- depthwise 3x3 conv + BN ----------
__global__ void conv_bn_kernel(const float* __restrict__ x1, const float* __restrict__ w,
                               const float* __restrict__ bng, const float* __restrict__ bnb,
                               const float* __restrict__ bnm, const float* __restrict__ bnv,
                               float* __restrict__ x2) {
  const size_t total = (size_t)32 * 784 * 576;
  const size_t idx = (size_t)blockIdx.x * 256 + threadIdx.x;
  if (idx >= total) return;
  const int c = (int)(idx % 576);
  const size_t p = idx / 576;
  const int pix = (int)(p % 784);
  const int b = (int)(p / 784);
  const int i = pix / 28, j = pix % 28;
  float acc = 0.f;
#pragma unroll
  for (int dh = -1; dh <= 1; ++dh) {
#pragma unroll
    for (int dw = -1; dw <= 1; ++dw) {
      const int ii = i + dh, jj = j + dw;
      if (ii >= 0 && ii < 28 && jj >= 0 && jj < 28)
        acc += x1[((size_t)b * 784 + ii * 28 + jj) * 576 + c] * w[c * 9 + (dh + 1) * 3 + (dw + 1)];
    }
  }
  const float inv = rsqrtf(bnv[c] + 1e-5f);
  x2[idx] = (acc - bnm[c]) * (inv * bng[c]) + bnb[c];
}

// ---------- launch ----------
extern "C" void kernel_launch(void* const* d_in, const int* in_sizes, int n_in,
                              void* d_out, int out_size, void* d_ws, size_t ws_size,
                              hipStream_t stream) {
  (void)in_sizes; (void)n_in; (void)out_size; (void)ws_size;
  const float* x      = (const float*)d_in[0];
  const float* ln1g   = (const float*)d_in[1];
  const float* ln1b   = (const float*)d_in[2];
  const float* qkv_w  = (const float*)d_in[3];
  const float* qkv_b  = (const float*)d_in[4];
  const float* biases = (const float*)d_in[5];
  const float* proj_w = (const float*)d_in[6];
  const float* proj_b = (const float*)d_in[7];
  const float* conv_w = (const float*)d_in[8];
  const float* bng    = (const float*)d_in[9];
  const float* bnb    = (const float*)d_in[10];
  const float* bnm    = (const float*)d_in[11];
  const float* bnv    = (const float*)d_in[12];
  const float* ln2g   = (const float*)d_in[13];
  const float* ln2b   = (const float*)d_in[14];
  const float* fc1_w  = (const float*)d_in[15];
  const float* fc1_b  = (const float*)d_in[16];
  const float* fc2_w  = (const float*)d_in[17];
  const float* fc2_b  = (const float*)d_in[18];
  float* out = (float*)d_out;

  const int M = 25088;
  char* ws = (char*)d_ws;
  // Workspace (210.3 MB total):
  //   A [0, 57802752)           : x2 f32 (M x 576)                 live step5->end
  //   B [57802752, +115605504)  : qkv bf16 (Mx1728) -> x1 f32 (Mx576) -> hm bf16 (Mx2304)
  //   C [173408256, +28901376)  : xn1 bf16 -> o bf16 -> xn2 bf16
  //   D [202309632, +7962624)   : transposed bf16 weights
  float* x2 = (float*)ws;
  char* regB = ws + 57802752;
  __hip_bfloat16* qkvb = (__hip_bfloat16*)regB;
  float*          x1   = (float*)regB;
  __hip_bfloat16* hm   = (__hip_bfloat16*)regB;
  char* regC = ws + 173408256;
  __hip_bfloat16* xn1  = (__hip_bfloat16*)regC;
  __hip_bfloat16* obuf = (__hip_bfloat16*)regC;
  __hip_bfloat16* xn2  = (__hip_bfloat16*)regC;
  char* regD = ws + 202309632;
  __hip_bfloat16* qkvT = (__hip_bfloat16*)regD;
  __hip_bfloat16* projT = (__hip_bfloat16*)(regD + 1990656);
  __hip_bfloat16* fc1T  = (__hip_bfloat16*)(regD + 1990656 + 663552);
  __hip_bfloat16* fc2T  = (__hip_bfloat16*)(regD + 1990656 + 663552 + 2654208);

  // weight prep (bf16, transposed to [N][K])
  wt_kernel<<<dim3(1728 / 32, 576 / 32), 256, 0, stream>>>(qkv_w, qkvT, 576, 1728);
  wt_kernel<<<dim3(576 / 32, 576 / 32), 256, 0, stream>>>(proj_w, projT, 576, 576);
  wt_kernel<<<dim3(2304 / 32, 576 / 32), 256, 0, stream>>>(fc1_w, fc1T, 576, 2304);
  wt_kernel<<<dim3(576 / 32, 2304 / 32), 256, 0, stream>>>(fc2_w, fc2T, 2304, 576);

  // 1. xn1 = LN1(x) bf16
  ln_bf16_kernel<<<M / 4, 256, 0, stream>>>(x, ln1g, ln1b, xn1);
  // 2. qkv = xn1 @ qkv_w + qkv_b (bf16 out)
  gemm_bt<0, __hip_bfloat16><<<dim3(27, 196), 256, 0, stream>>>(xn1, qkvT, qkv_b, nullptr, qkvb, M, 1728, 576);
  // 3. attention
  attn_kernel<<<512 * 18, 256, 0, stream>>>(qkvb, biases, obuf);
  // 4. x1 = x + (o @ proj_w + proj_b)
  gemm_bt<1, float><<<dim3(9, 196), 256, 0, stream>>>(obuf, projT, proj_b, x, x1, M, 576, 576);
  // 5. x2 = BN(dwconv(x1))
  conv_bn_kernel<<<(32 * 784 * 576 + 255) / 256, 256, 0, stream>>>(x1, conv_w, bng, bnb, bnm, bnv, x2);
  // 6. xn2 = LN2(x2) bf16
  ln_bf16_kernel<<<M / 4, 256, 0, stream>>>(x2, ln2g, ln2b, xn2);
  // 7. hm = gelu(xn2 @ fc1_w + fc1_b) bf16
  gemm_bt<2, __hip_bfloat16><<<dim3(36, 196), 256, 0, stream>>>(xn2, fc1T, fc1_b, nullptr, hm, M, 2304, 576);
  // 8. out = x2 + (hm @ fc2_w + fc2_b)
  gemm_bt<1, float><<<dim3(9, 196), 256, 0, stream>>>(hm, fc2T, fc2_b, x2, out, M, 576, 2304);
}

// Round 6
// 697.908 us; speedup vs baseline: 6.0135x; 1.2815x over previous
//
#include <hip/hip_runtime.h>
#include <hip/hip_bf16.h>

typedef __attribute__((ext_vector_type(8))) short bf16x8;
typedef __attribute__((ext_vector_type(4))) float f32x4;

static __device__ __forceinline__ void stf(float* p, size_t i, float v) { p[i] = v; }
static __device__ __forceinline__ void stf(__hip_bfloat16* p, size_t i, float v) { p[i] = __float2bfloat16(v); }

static __device__ __forceinline__ void gload_lds16(const void* g, void* l) {
  __builtin_amdgcn_global_load_lds((const __attribute__((address_space(1))) void*)g,
                                   (__attribute__((address_space(3))) void*)l, 16, 0, 0);
}

// ---------- weight transpose + bf16 convert: W[K][N] f32 -> WT[N][K] bf16 ----------
__global__ void wt_kernel(const float* __restrict__ W, __hip_bfloat16* __restrict__ WT, int K, int N) {
  __shared__ float tile[32][33];
  const int kb = blockIdx.y * 32, nb = blockIdx.x * 32;
  const int tx = threadIdx.x & 31, ty = threadIdx.x >> 5;  // 256 thr: ty 0..7
#pragma unroll
  for (int i = 0; i < 4; ++i)
    tile[ty + i * 8][tx] = W[(size_t)(kb + ty + i * 8) * N + nb + tx];
  __syncthreads();
#pragma unroll
  for (int i = 0; i < 4; ++i)
    WT[(size_t)(nb + ty + i * 8) * K + kb + tx] = __float2bfloat16(tile[tx][ty + i * 8]);
}

// ---------- fused LN -> bf16: one wave per 576-elem row ----------
__global__ void ln_bf16_kernel(const float* __restrict__ x, const float* __restrict__ g,
                               const float* __restrict__ b, __hip_bfloat16* __restrict__ y) {
  const int row = blockIdx.x * 4 + (threadIdx.x >> 6);
  const int lane = threadIdx.x & 63;
  const float* p = x + (size_t)row * 576;
  float vals[9];
  float s = 0.f, ss = 0.f;
#pragma unroll
  for (int i = 0; i < 9; ++i) {
    float v = p[lane + i * 64];
    vals[i] = v; s += v; ss += v * v;
  }
#pragma unroll
  for (int o = 32; o; o >>= 1) { s += __shfl_down(s, o); ss += __shfl_down(ss, o); }
  s = __shfl(s, 0); ss = __shfl(ss, 0);
  const float m = s * (1.f / 576.f);
  const float rstd = rsqrtf(ss * (1.f / 576.f) - m * m + 1e-5f);
  __hip_bfloat16* q = y + (size_t)row * 576;
#pragma unroll
  for (int i = 0; i < 9; ++i) {
    const int c = lane + i * 64;
    q[c] = __float2bfloat16((vals[i] - m) * rstd * g[c] + b[c]);
  }
}

// ---------- MFMA GEMM: C[M,N] = epi(A[M,K] @ BT[N,K]^T + bias) ----------
// tile 128x64, BK=64, 4 waves (2x2), mfma_f32_16x16x32_bf16, gload_lds + XOR swizzle.
// EPI: 0 none, 1 +res, 2 exact GELU
template <int EPI, typename TO>
__global__ __launch_bounds__(256) void gemm_bt(
    const __hip_bfloat16* __restrict__ A, const __hip_bfloat16* __restrict__ BT,
    const float* __restrict__ bias, const float* __restrict__ res, TO* __restrict__ C,
    int M, int N, int K) {
  __shared__ __hip_bfloat16 sA[2][128 * 64];
  __shared__ __hip_bfloat16 sB[2][64 * 64];
  const int t = threadIdx.x;
  const int lane = t & 63;
  const int w = t >> 6;
  const int bm = blockIdx.y * 128, bn = blockIdx.x * 64;
  const int wm = (w >> 1) * 64, wn = (w & 1) * 32;
  const int l15 = lane & 15, l4 = lane >> 4;

  f32x4 acc[4][2];
#pragma unroll
  for (int mi = 0; mi < 4; ++mi)
#pragma unroll
    for (int ni = 0; ni < 2; ++ni) acc[mi][ni] = (f32x4){0.f, 0.f, 0.f, 0.f};

  const int wave_base = t & ~63;  // wave-uniform

  auto stage = [&](int buf, int k0) {
#pragma unroll
    for (int i = 0; i < 4; ++i) {
      const int slot = i * 256 + t;
      const int row = slot >> 3, kst = slot & 7;
      const int ksrc = kst ^ (row & 7);
      const __hip_bfloat16* g = A + (size_t)(bm + row) * K + k0 + ksrc * 8;
      gload_lds16(g, sA[buf] + (i * 256 + wave_base) * 8);
    }
#pragma unroll
    for (int i = 0; i < 2; ++i) {
      const int slot = i * 256 + t;
      const int row = slot >> 3, kst = slot & 7;
      const int ksrc = kst ^ (row & 7);
      const __hip_bfloat16* g = BT + (size_t)(bn + row) * K + k0 + ksrc * 8;
      gload_lds16(g, sB[buf] + (i * 256 + wave_base) * 8);
    }
  };

  auto compute = [&](int buf) {
    const __hip_bfloat16* pA = sA[buf];
    const __hip_bfloat16* pB = sB[buf];
#pragma unroll
    for (int kb = 0; kb < 2; ++kb) {
      bf16x8 a[4], b[2];
      const int kblk = kb * 4 + l4;
#pragma unroll
      for (int mi = 0; mi < 4; ++mi) {
        const int row = wm + mi * 16 + l15;
        a[mi] = *(const bf16x8*)(pA + row * 64 + ((kblk ^ (row & 7)) * 8));
      }
#pragma unroll
      for (int ni = 0; ni < 2; ++ni) {
        const int row = wn + ni * 16 + l15;
        b[ni] = *(const bf16x8*)(pB + row * 64 + ((kblk ^ (row & 7)) * 8));
      }
#pragma unroll
      for (int mi = 0; mi < 4; ++mi)
#pragma unroll
        for (int ni = 0; ni < 2; ++ni)
          acc[mi][ni] = __builtin_amdgcn_mfma_f32_16x16x32_bf16(a[mi], b[ni], acc[mi][ni], 0, 0, 0);
    }
  };

  const int nt = K >> 6;
  stage(0, 0);
  __syncthreads();
  int cur = 0;
  for (int tt = 0; tt < nt - 1; ++tt) {
    stage(cur ^ 1, (tt + 1) << 6);
    compute(cur);
    __syncthreads();
    cur ^= 1;
  }
  compute(cur);

  // epilogue: C/D layout col=lane&15, row=(lane>>4)*4+reg
#pragma unroll
  for (int mi = 0; mi < 4; ++mi) {
    const int mrow = bm + wm + mi * 16 + l4 * 4;
#pragma unroll
    for (int ni = 0; ni < 2; ++ni) {
      const int col = bn + wn + ni * 16 + l15;
      const float bv = bias[col];
#pragma unroll
      for (int r = 0; r < 4; ++r) {
        const size_t idx = (size_t)(mrow + r) * N + col;
        float v = acc[mi][ni][r] + bv;
        if (EPI == 1) v += res[idx];
        if (EPI == 2) v = 0.5f * v * (1.0f + erff(v * 0.70710678118654752f));
        stf(C, idx, v);
      }
    }
  }
}

// ---------- MFMA windowed attention: 1 wave per (window, head) ----------
// Q(49x32)@K^T via 16 mfma (pad to 64), wave-parallel softmax (shfl_xor over
// 16-lane row groups), P(bf16)@V via 16 mfma with V pre-transposed in LDS.
// Pad rows/cols: masked to -1e30 before softmax; NaN from garbage pads is
// confined to output rows i>=49 which are never stored.
__global__ __launch_bounds__(64) void attn_mfma_kernel(
    const __hip_bfloat16* __restrict__ qkv, const float* __restrict__ biases,
    __hip_bfloat16* __restrict__ o) {
  __shared__ __hip_bfloat16 sQK[2][64][40];  // Q, K (stride 40 -> 80B, 16B-aligned rows)
  __shared__ __hip_bfloat16 sVT[32][72];     // V transposed [d][token], stride 72 -> 144B
  __hip_bfloat16 (*sP)[72] = (__hip_bfloat16(*)[72])(&sQK[0][0][0]);  // P reuses Q+K region

  const int wid  = blockIdx.x / 18;
  const int head = blockIdx.x - wid * 18;
  const int b  = wid >> 4;
  const int wi = wid & 15;
  const int wh = wi >> 2, wwc = wi & 3;
  const int lane = threadIdx.x;
  const int l15 = lane & 15, l4 = lane >> 4;

  // ---- stage Q, K, V^T from qkv[token][head*96 + {q,k,v}*32] ----
  {
    const __hip_bfloat16* basep = qkv + (size_t)head * 96;
    for (int idx = lane; idx < 49 * 12; idx += 64) {
      const int tkn = idx / 12, part = idx - tkn * 12;
      const int r = tkn / 7, c = tkn - r * 7;
      const size_t row = (size_t)b * 784 + (size_t)((wh * 7 + r) * 28 + wwc * 7 + c);
      bf16x8 v = *(const bf16x8*)(basep + row * 1728 + part * 8);
      if (part < 4)      *(bf16x8*)&sQK[0][tkn][part * 8] = v;
      else if (part < 8) *(bf16x8*)&sQK[1][tkn][(part - 4) * 8] = v;
      else {
        const int d0 = (part - 8) * 8;
        const short* sv = (const short*)&v;
#pragma unroll
        for (int e = 0; e < 8; ++e)
          sVT[d0 + e][tkn] = *(const __hip_bfloat16*)&sv[e];
      }
    }
    // zero VT pad cols 49..63 (P=0 there would still multiply garbage -> NaN)
    for (int idx = lane; idx < 32 * 15; idx += 64) {
      const int d = idx / 15, tt = 49 + (idx - d * 15);
      sVT[d][tt] = __float2bfloat16(0.0f);
    }
  }
  __syncthreads();

  // ---- S = Q @ K^T (64x64 padded) ----
  f32x4 acc[4][4];
#pragma unroll
  for (int mi = 0; mi < 4; ++mi)
#pragma unroll
    for (int ni = 0; ni < 4; ++ni) acc[mi][ni] = (f32x4){0.f, 0.f, 0.f, 0.f};
  {
    bf16x8 aq[4], bk[4];
#pragma unroll
    for (int mi = 0; mi < 4; ++mi) aq[mi] = *(const bf16x8*)&sQK[0][mi * 16 + l15][l4 * 8];
#pragma unroll
    for (int ni = 0; ni < 4; ++ni) bk[ni] = *(const bf16x8*)&sQK[1][ni * 16 + l15][l4 * 8];
#pragma unroll
    for (int mi = 0; mi < 4; ++mi)
#pragma unroll
      for (int ni = 0; ni < 4; ++ni)
        acc[mi][ni] = __builtin_amdgcn_mfma_f32_16x16x32_bf16(aq[mi], bk[ni], acc[mi][ni], 0, 0, 0);
  }
  __syncthreads();  // Q/K reads complete before P overwrites the region

  // ---- bias + masked wave-parallel softmax; P -> bf16 LDS ----
  // acc fragment: row = mi*16 + l4*4 + rr, col = ni*16 + l15 (row owned by 16
  // consecutive lanes l4*16..l4*16+15 -> shfl_xor 1/2/4/8 reduces over cols)
  const float scale = 0.17677669529663687f;  // 32^-0.5
  const float* btab = biases + head * 49;
#pragma unroll
  for (int mi = 0; mi < 4; ++mi) {
#pragma unroll
    for (int rr = 0; rr < 4; ++rr) {
      const int i = mi * 16 + l4 * 4 + rr;
      const int ic = i < 49 ? i : 0;  // clamp for valid bias indexing on dead rows
      const int ri = ic / 7, ci = ic - ri * 7;
      float s[4];
#pragma unroll
      for (int ni = 0; ni < 4; ++ni) {
        const int j = ni * 16 + l15;
        if (j < 49) {
          const int rj = j / 7, cj = j - rj * 7;
          s[ni] = acc[mi][ni][rr] * scale + btab[__builtin_abs(ri - rj) * 7 + __builtin_abs(ci - cj)];
        } else {
          s[ni] = -1e30f;
        }
      }
      float m = fmaxf(fmaxf(s[0], s[1]), fmaxf(s[2], s[3]));
#pragma unroll
      for (int d = 1; d < 16; d <<= 1) m = fmaxf(m, __shfl_xor(m, d));
      float sum = 0.f;
#pragma unroll
      for (int ni = 0; ni < 4; ++ni) { s[ni] = __expf(s[ni] - m); sum += s[ni]; }
#pragma unroll
      for (int d = 1; d < 16; d <<= 1) sum += __shfl_xor(sum, d);
      const float inv = 1.0f / sum;
#pragma unroll
      for (int ni = 0; ni < 4; ++ni)
        sP[i][ni * 16 + l15] = __float2bfloat16(s[ni] * inv);
    }
  }
  __syncthreads();

  // ---- O = P @ V  (contract j over 2 k-blocks of 32) ----
  f32x4 oacc[4][2];
#pragma unroll
  for (int mi = 0; mi < 4; ++mi)
#pragma unroll
    for (int ni = 0; ni < 2; ++ni) oacc[mi][ni] = (f32x4){0.f, 0.f, 0.f, 0.f};
#pragma unroll
  for (int kb = 0; kb < 2; ++kb) {
    bf16x8 ap[4], bv[2];
#pragma unroll
    for (int mi = 0; mi < 4; ++mi) ap[mi] = *(const bf16x8*)&sP[mi * 16 + l15][kb * 32 + l4 * 8];
#pragma unroll
    for (int ni = 0; ni < 2; ++ni) bv[ni] = *(const bf16x8*)&sVT[ni * 16 + l15][kb * 32 + l4 * 8];
#pragma unroll
    for (int mi = 0; mi < 4; ++mi)
#pragma unroll
      for (int ni = 0; ni < 2; ++ni)
        oacc[mi][ni] = __builtin_amdgcn_mfma_f32_16x16x32_bf16(ap[mi], bv[ni], oacc[mi][ni], 0, 0, 0);
  }

  // ---- store O rows < 49 ----
#pragma unroll
  for (int mi = 0; mi < 4; ++mi) {
#pragma unroll
    for (int rr = 0; rr < 4; ++rr) {
      const int i = mi * 16 + l4 * 4 + rr;
      if (i < 49) {
        const int r = i / 7, c = i - r * 7;
        const size_t grow = (size_t)b * 784 + (size_t)((wh * 7 + r) * 28 + wwc * 7 + c);
#pragma unroll
        for (int ni = 0; ni < 2; ++ni)
          o[grow * 576 + head * 32 + ni * 16 + l15] = __float2bfloat16(oacc[mi][ni][rr]);
      }
    }
  }
}

// ---------- depthwise 3x3 conv + BN ----------
__global__ void conv_bn_kernel(const float* __restrict__ x1, const float* __restrict__ w,
                               const float* __restrict__ bng, const float* __restrict__ bnb,
                               const float* __restrict__ bnm, const float* __restrict__ bnv,
                               float* __restrict__ x2) {
  const size_t total = (size_t)32 * 784 * 576;
  const size_t idx = (size_t)blockIdx.x * 256 + threadIdx.x;
  if (idx >= total) return;
  const int c = (int)(idx % 576);
  const size_t p = idx / 576;
  const int pix = (int)(p % 784);
  const int b = (int)(p / 784);
  const int i = pix / 28, j = pix % 28;
  float acc = 0.f;
#pragma unroll
  for (int dh = -1; dh <= 1; ++dh) {
#pragma unroll
    for (int dw = -1; dw <= 1; ++dw) {
      const int ii = i + dh, jj = j + dw;
      if (ii >= 0 && ii < 28 && jj >= 0 && jj < 28)
        acc += x1[((size_t)b * 784 + ii * 28 + jj) * 576 + c] * w[c * 9 + (dh + 1) * 3 + (dw + 1)];
    }
  }
  const float inv = rsqrtf(bnv[c] + 1e-5f);
  x2[idx] = (acc - bnm[c]) * (inv * bng[c]) + bnb[c];
}

// ---------- launch ----------
extern "C" void kernel_launch(void* const* d_in, const int* in_sizes, int n_in,
                              void* d_out, int out_size, void* d_ws, size_t ws_size,
                              hipStream_t stream) {
  (void)in_sizes; (void)n_in; (void)out_size; (void)ws_size;
  const float* x      = (const float*)d_in[0];
  const float* ln1g   = (const float*)d_in[1];
  const float* ln1b   = (const float*)d_in[2];
  const float* qkv_w  = (const float*)d_in[3];
  const float* qkv_b  = (const float*)d_in[4];
  const float* biases = (const float*)d_in[5];
  const float* proj_w = (const float*)d_in[6];
  const float* proj_b = (const float*)d_in[7];
  const float* conv_w = (const float*)d_in[8];
  const float* bng    = (const float*)d_in[9];
  const float* bnb    = (const float*)d_in[10];
  const float* bnm    = (const float*)d_in[11];
  const float* bnv    = (const float*)d_in[12];
  const float* ln2g   = (const float*)d_in[13];
  const float* ln2b   = (const float*)d_in[14];
  const float* fc1_w  = (const float*)d_in[15];
  const float* fc1_b  = (const float*)d_in[16];
  const float* fc2_w  = (const float*)d_in[17];
  const float* fc2_b  = (const float*)d_in[18];
  float* out = (float*)d_out;

  const int M = 25088;
  char* ws = (char*)d_ws;
  // Workspace (210.3 MB total):
  //   A [0, 57802752)           : x2 f32 (M x 576)                 live step5->end
  //   B [57802752, +115605504)  : qkv bf16 (Mx1728) -> x1 f32 (Mx576) -> hm bf16 (Mx2304)
  //   C [173408256, +28901376)  : xn1 bf16 -> o bf16 -> xn2 bf16
  //   D [202309632, +7962624)   : transposed bf16 weights
  float* x2 = (float*)ws;
  char* regB = ws + 57802752;
  __hip_bfloat16* qkvb = (__hip_bfloat16*)regB;
  float*          x1   = (float*)regB;
  __hip_bfloat16* hm   = (__hip_bfloat16*)regB;
  char* regC = ws + 173408256;
  __hip_bfloat16* xn1  = (__hip_bfloat16*)regC;
  __hip_bfloat16* obuf = (__hip_bfloat16*)regC;
  __hip_bfloat16* xn2  = (__hip_bfloat16*)regC;
  char* regD = ws + 202309632;
  __hip_bfloat16* qkvT = (__hip_bfloat16*)regD;
  __hip_bfloat16* projT = (__hip_bfloat16*)(regD + 1990656);
  __hip_bfloat16* fc1T  = (__hip_bfloat16*)(regD + 1990656 + 663552);
  __hip_bfloat16* fc2T  = (__hip_bfloat16*)(regD + 1990656 + 663552 + 2654208);

  // weight prep (bf16, transposed to [N][K])
  wt_kernel<<<dim3(1728 / 32, 576 / 32), 256, 0, stream>>>(qkv_w, qkvT, 576, 1728);
  wt_kernel<<<dim3(576 / 32, 576 / 32), 256, 0, stream>>>(proj_w, projT, 576, 576);
  wt_kernel<<<dim3(2304 / 32, 576 / 32), 256, 0, stream>>>(fc1_w, fc1T, 576, 2304);
  wt_kernel<<<dim3(576 / 32, 2304 / 32), 256, 0, stream>>>(fc2_w, fc2T, 2304, 576);

  // 1. xn1 = LN1(x) bf16
  ln_bf16_kernel<<<M / 4, 256, 0, stream>>>(x, ln1g, ln1b, xn1);
  // 2. qkv = xn1 @ qkv_w + qkv_b (bf16 out)
  gemm_bt<0, __hip_bfloat16><<<dim3(27, 196), 256, 0, stream>>>(xn1, qkvT, qkv_b, nullptr, qkvb, M, 1728, 576);
  // 3. attention (MFMA, 1 wave per window-head)
  attn_mfma_kernel<<<512 * 18, 64, 0, stream>>>(qkvb, biases, obuf);
  // 4. x1 = x + (o @ proj_w + proj_b)
  gemm_bt<1, float><<<dim3(9, 196), 256, 0, stream>>>(obuf, projT, proj_b, x, x1, M, 576, 576);
  // 5. x2 = BN(dwconv(x1))
  conv_bn_kernel<<<(32 * 784 * 576 + 255) / 256, 256, 0, stream>>>(x1, conv_w, bng, bnb, bnm, bnv, x2);
  // 6. xn2 = LN2(x2) bf16
  ln_bf16_kernel<<<M / 4, 256, 0, stream>>>(x2, ln2g, ln2b, xn2);
  // 7. hm = gelu(xn2 @ fc1_w + fc1_b) bf16
  gemm_bt<2, __hip_bfloat16><<<dim3(36, 196), 256, 0, stream>>>(xn2, fc1T, fc1_b, nullptr, hm, M, 2304, 576);
  // 8. out = x2 + (hm @ fc2_w + fc2_b)
  gemm_bt<1, float><<<dim3(9, 196), 256, 0, stream>>>(hm, fc2T, fc2_b, x2, out, M, 576, 2304);
}

// Round 7
// 571.144 us; speedup vs baseline: 7.3482x; 1.2219x over previous
//
#include <hip/hip_runtime.h>
#include <hip/hip_bf16.h>

typedef __attribute__((ext_vector_type(8))) short bf16x8;
typedef __attribute__((ext_vector_type(4))) float f32x4;

static __device__ __forceinline__ void stf(float* p, size_t i, float v) { p[i] = v; }
static __device__ __forceinline__ void stf(__hip_bfloat16* p, size_t i, float v) { p[i] = __float2bfloat16(v); }

static __device__ __forceinline__ void gload_lds16(const void* g, void* l) {
  __builtin_amdgcn_global_load_lds((const __attribute__((address_space(1))) void*)g,
                                   (__attribute__((address_space(3))) void*)l, 16, 0, 0);
}

// ---------- weight transpose + bf16 convert: W[K][N] f32 -> WT[N][K] bf16 ----------
__global__ void wt_kernel(const float* __restrict__ W, __hip_bfloat16* __restrict__ WT, int K, int N) {
  __shared__ float tile[32][33];
  const int kb = blockIdx.y * 32, nb = blockIdx.x * 32;
  const int tx = threadIdx.x & 31, ty = threadIdx.x >> 5;
#pragma unroll
  for (int i = 0; i < 4; ++i)
    tile[ty + i * 8][tx] = W[(size_t)(kb + ty + i * 8) * N + nb + tx];
  __syncthreads();
#pragma unroll
  for (int i = 0; i < 4; ++i)
    WT[(size_t)(nb + ty + i * 8) * K + kb + tx] = __float2bfloat16(tile[tx][ty + i * 8]);
}

// ---------- conv prep: wT[tap][c] = w[c*9+tap]; s[c]=rsqrt(var+eps)*g; t[c]=b-mean*s ----------
__global__ void convprep_kernel(const float* __restrict__ w, const float* __restrict__ bng,
                                const float* __restrict__ bnb, const float* __restrict__ bnm,
                                const float* __restrict__ bnv, float* __restrict__ wT,
                                float* __restrict__ st) {
  const int i = blockIdx.x * 256 + threadIdx.x;
  if (i < 576 * 9) {
    const int t = i / 576, c = i - t * 576;
    wT[i] = w[c * 9 + t];
  }
  if (i < 576) {
    const float s = rsqrtf(bnv[i] + 1e-5f) * bng[i];
    st[i] = s;
    st[576 + i] = bnb[i] - bnm[i] * s;
  }
}

// ---------- fused LN -> bf16: one wave per 576-elem row ----------
__global__ void ln_bf16_kernel(const float* __restrict__ x, const float* __restrict__ g,
                               const float* __restrict__ b, __hip_bfloat16* __restrict__ y) {
  const int row = blockIdx.x * 4 + (threadIdx.x >> 6);
  const int lane = threadIdx.x & 63;
  const float* p = x + (size_t)row * 576;
  float vals[9];
  float s = 0.f, ss = 0.f;
#pragma unroll
  for (int i = 0; i < 9; ++i) {
    float v = p[lane + i * 64];
    vals[i] = v; s += v; ss += v * v;
  }
#pragma unroll
  for (int o = 32; o; o >>= 1) { s += __shfl_down(s, o); ss += __shfl_down(ss, o); }
  s = __shfl(s, 0); ss = __shfl(ss, 0);
  const float m = s * (1.f / 576.f);
  const float rstd = rsqrtf(ss * (1.f / 576.f) - m * m + 1e-5f);
  __hip_bfloat16* q = y + (size_t)row * 576;
#pragma unroll
  for (int i = 0; i < 9; ++i) {
    const int c = lane + i * 64;
    q[c] = __float2bfloat16((vals[i] - m) * rstd * g[c] + b[c]);
  }
}

// ---------- MFMA GEMM: C[M,N] = epi(A[M,K] @ BT[N,K]^T + bias) ----------
// tile 128x64, BK=64, 4 waves (2x2), gload_lds + XOR swizzle.
// 1D grid, panel-major (col-fastest) + bijective XCD swizzle (m204): the nx
// col-blocks sharing one A-panel run on ONE XCD -> panel fetched once, reused
// from that XCD's L2; B (<=2.65MB) also L2-resident per XCD.
// EPI: 0 none, 1 +res, 2 exact GELU
template <int EPI, typename TO>
__global__ __launch_bounds__(256) void gemm_bt(
    const __hip_bfloat16* __restrict__ A, const __hip_bfloat16* __restrict__ BT,
    const float* __restrict__ bias, const float* __restrict__ res, TO* __restrict__ C,
    int M, int N, int K) {
  __shared__ __hip_bfloat16 sA[2][128 * 64];
  __shared__ __hip_bfloat16 sB[2][64 * 64];
  const int t = threadIdx.x;
  const int lane = t & 63;
  const int w = t >> 6;
  // bijective XCD swizzle
  const int nwg = gridDim.x;
  const int q = nwg >> 3, r = nwg & 7;
  const int xcd = blockIdx.x & 7, lidx = blockIdx.x >> 3;
  const int wgid = (xcd < r ? xcd * (q + 1) : r * (q + 1) + (xcd - r) * q) + lidx;
  const int nx = N >> 6;
  const int bm = (wgid / nx) * 128, bn = (wgid % nx) * 64;
  const int wm = (w >> 1) * 64, wn = (w & 1) * 32;
  const int l15 = lane & 15, l4 = lane >> 4;

  f32x4 acc[4][2];
#pragma unroll
  for (int mi = 0; mi < 4; ++mi)
#pragma unroll
    for (int ni = 0; ni < 2; ++ni) acc[mi][ni] = (f32x4){0.f, 0.f, 0.f, 0.f};

  const int wave_base = t & ~63;

  auto stage = [&](int buf, int k0) {
#pragma unroll
    for (int i = 0; i < 4; ++i) {
      const int slot = i * 256 + t;
      const int row = slot >> 3, kst = slot & 7;
      const int ksrc = kst ^ (row & 7);
      const __hip_bfloat16* g = A + (size_t)(bm + row) * K + k0 + ksrc * 8;
      gload_lds16(g, sA[buf] + (i * 256 + wave_base) * 8);
    }
#pragma unroll
    for (int i = 0; i < 2; ++i) {
      const int slot = i * 256 + t;
      const int row = slot >> 3, kst = slot & 7;
      const int ksrc = kst ^ (row & 7);
      const __hip_bfloat16* g = BT + (size_t)(bn + row) * K + k0 + ksrc * 8;
      gload_lds16(g, sB[buf] + (i * 256 + wave_base) * 8);
    }
  };

  auto compute = [&](int buf) {
    const __hip_bfloat16* pA = sA[buf];
    const __hip_bfloat16* pB = sB[buf];
#pragma unroll
    for (int kb = 0; kb < 2; ++kb) {
      bf16x8 a[4], b[2];
      const int kblk = kb * 4 + l4;
#pragma unroll
      for (int mi = 0; mi < 4; ++mi) {
        const int row = wm + mi * 16 + l15;
        a[mi] = *(const bf16x8*)(pA + row * 64 + ((kblk ^ (row & 7)) * 8));
      }
#pragma unroll
      for (int ni = 0; ni < 2; ++ni) {
        const int row = wn + ni * 16 + l15;
        b[ni] = *(const bf16x8*)(pB + row * 64 + ((kblk ^ (row & 7)) * 8));
      }
#pragma unroll
      for (int mi = 0; mi < 4; ++mi)
#pragma unroll
        for (int ni = 0; ni < 2; ++ni)
          acc[mi][ni] = __builtin_amdgcn_mfma_f32_16x16x32_bf16(a[mi], b[ni], acc[mi][ni], 0, 0, 0);
    }
  };

  const int nt = K >> 6;
  stage(0, 0);
  __syncthreads();
  int cur = 0;
  for (int tt = 0; tt < nt - 1; ++tt) {
    stage(cur ^ 1, (tt + 1) << 6);
    compute(cur);
    __syncthreads();
    cur ^= 1;
  }
  compute(cur);

#pragma unroll
  for (int mi = 0; mi < 4; ++mi) {
    const int mrow = bm + wm + mi * 16 + l4 * 4;
#pragma unroll
    for (int ni = 0; ni < 2; ++ni) {
      const int col = bn + wn + ni * 16 + l15;
      const float bv = bias[col];
#pragma unroll
      for (int r2 = 0; r2 < 4; ++r2) {
        const size_t idx = (size_t)(mrow + r2) * N + col;
        float v = acc[mi][ni][r2] + bv;
        if (EPI == 1) v += res[idx];
        if (EPI == 2) v = 0.5f * v * (1.0f + erff(v * 0.70710678118654752f));
        stf(C, idx, v);
      }
    }
  }
}

// ---------- MFMA windowed attention: 1 wave per (window, head) ----------
__global__ __launch_bounds__(64) void attn_mfma_kernel(
    const __hip_bfloat16* __restrict__ qkv, const float* __restrict__ biases,
    __hip_bfloat16* __restrict__ o) {
  __shared__ __hip_bfloat16 sQK[2][64][40];
  __shared__ __hip_bfloat16 sVT[32][72];
  __hip_bfloat16 (*sP)[72] = (__hip_bfloat16(*)[72])(&sQK[0][0][0]);

  const int wid  = blockIdx.x / 18;
  const int head = blockIdx.x - wid * 18;
  const int b  = wid >> 4;
  const int wi = wid & 15;
  const int wh = wi >> 2, wwc = wi & 3;
  const int lane = threadIdx.x;
  const int l15 = lane & 15, l4 = lane >> 4;

  {
    const __hip_bfloat16* basep = qkv + (size_t)head * 96;
    for (int idx = lane; idx < 49 * 12; idx += 64) {
      const int tkn = idx / 12, part = idx - tkn * 12;
      const int r = tkn / 7, c = tkn - r * 7;
      const size_t row = (size_t)b * 784 + (size_t)((wh * 7 + r) * 28 + wwc * 7 + c);
      bf16x8 v = *(const bf16x8*)(basep + row * 1728 + part * 8);
      if (part < 4)      *(bf16x8*)&sQK[0][tkn][part * 8] = v;
      else if (part < 8) *(bf16x8*)&sQK[1][tkn][(part - 4) * 8] = v;
      else {
        const int d0 = (part - 8) * 8;
        const short* sv = (const short*)&v;
#pragma unroll
        for (int e = 0; e < 8; ++e)
          sVT[d0 + e][tkn] = *(const __hip_bfloat16*)&sv[e];
      }
    }
    for (int idx = lane; idx < 32 * 15; idx += 64) {
      const int d = idx / 15, tt = 49 + (idx - d * 15);
      sVT[d][tt] = __float2bfloat16(0.0f);
    }
  }
  __syncthreads();

  f32x4 acc[4][4];
#pragma unroll
  for (int mi = 0; mi < 4; ++mi)
#pragma unroll
    for (int ni = 0; ni < 4; ++ni) acc[mi][ni] = (f32x4){0.f, 0.f, 0.f, 0.f};
  {
    bf16x8 aq[4], bk[4];
#pragma unroll
    for (int mi = 0; mi < 4; ++mi) aq[mi] = *(const bf16x8*)&sQK[0][mi * 16 + l15][l4 * 8];
#pragma unroll
    for (int ni = 0; ni < 4; ++ni) bk[ni] = *(const bf16x8*)&sQK[1][ni * 16 + l15][l4 * 8];
#pragma unroll
    for (int mi = 0; mi < 4; ++mi)
#pragma unroll
      for (int ni = 0; ni < 4; ++ni)
        acc[mi][ni] = __builtin_amdgcn_mfma_f32_16x16x32_bf16(aq[mi], bk[ni], acc[mi][ni], 0, 0, 0);
  }
  __syncthreads();

  const float scale = 0.17677669529663687f;
  const float* btab = biases + head * 49;
#pragma unroll
  for (int mi = 0; mi < 4; ++mi) {
#pragma unroll
    for (int rr = 0; rr < 4; ++rr) {
      const int i = mi * 16 + l4 * 4 + rr;
      const int ic = i < 49 ? i : 0;
      const int ri = ic / 7, ci = ic - ri * 7;
      float s[4];
#pragma unroll
      for (int ni = 0; ni < 4; ++ni) {
        const int j = ni * 16 + l15;
        if (j < 49) {
          const int rj = j / 7, cj = j - rj * 7;
          s[ni] = acc[mi][ni][rr] * scale + btab[__builtin_abs(ri - rj) * 7 + __builtin_abs(ci - cj)];
        } else {
          s[ni] = -1e30f;
        }
      }
      float m = fmaxf(fmaxf(s[0], s[1]), fmaxf(s[2], s[3]));
#pragma unroll
      for (int d = 1; d < 16; d <<= 1) m = fmaxf(m, __shfl_xor(m, d));
      float sum = 0.f;
#pragma unroll
      for (int ni = 0; ni < 4; ++ni) { s[ni] = __expf(s[ni] - m); sum += s[ni]; }
#pragma unroll
      for (int d = 1; d < 16; d <<= 1) sum += __shfl_xor(sum, d);
      const float inv = 1.0f / sum;
#pragma unroll
      for (int ni = 0; ni < 4; ++ni)
        sP[i][ni * 16 + l15] = __float2bfloat16(s[ni] * inv);
    }
  }
  __syncthreads();

  f32x4 oacc[4][2];
#pragma unroll
  for (int mi = 0; mi < 4; ++mi)
#pragma unroll
    for (int ni = 0; ni < 2; ++ni) oacc[mi][ni] = (f32x4){0.f, 0.f, 0.f, 0.f};
#pragma unroll
  for (int kb = 0; kb < 2; ++kb) {
    bf16x8 ap[4], bv[2];
#pragma unroll
    for (int mi = 0; mi < 4; ++mi) ap[mi] = *(const bf16x8*)&sP[mi * 16 + l15][kb * 32 + l4 * 8];
#pragma unroll
    for (int ni = 0; ni < 2; ++ni) bv[ni] = *(const bf16x8*)&sVT[ni * 16 + l15][kb * 32 + l4 * 8];
#pragma unroll
    for (int mi = 0; mi < 4; ++mi)
#pragma unroll
      for (int ni = 0; ni < 2; ++ni)
        oacc[mi][ni] = __builtin_amdgcn_mfma_f32_16x16x32_bf16(ap[mi], bv[ni], oacc[mi][ni], 0, 0, 0);
  }

#pragma unroll
  for (int mi = 0; mi < 4; ++mi) {
#pragma unroll
    for (int rr = 0; rr < 4; ++rr) {
      const int i = mi * 16 + l4 * 4 + rr;
      if (i < 49) {
        const int r = i / 7, c = i - r * 7;
        const size_t grow = (size_t)b * 784 + (size_t)((wh * 7 + r) * 28 + wwc * 7 + c);
#pragma unroll
        for (int ni = 0; ni < 2; ++ni)
          o[grow * 576 + head * 32 + ni * 16 + l15] = __float2bfloat16(oacc[mi][ni][rr]);
      }
    }
  }
}

// ---------- depthwise 3x3 conv + folded BN, float4 over channels ----------
__global__ void conv_bn_kernel(const float* __restrict__ x1, const float* __restrict__ wT,
                               const float* __restrict__ st, float* __restrict__ x2) {
  const size_t total = (size_t)32 * 784 * 144;  // float4 groups
  const size_t idx = (size_t)blockIdx.x * 256 + threadIdx.x;
  if (idx >= total) return;
  const int c4 = (int)(idx % 144);
  const size_t p = idx / 144;
  const int pix = (int)(p % 784);
  const int b = (int)(p / 784);
  const int i = pix / 28, j = pix - (pix / 28) * 28;
  const int c = c4 * 4;
  f32x4 acc = (f32x4){0.f, 0.f, 0.f, 0.f};
#pragma unroll
  for (int dh = -1; dh <= 1; ++dh) {
#pragma unroll
    for (int dw = -1; dw <= 1; ++dw) {
      const int ii = i + dh, jj = j + dw;
      if (ii >= 0 && ii < 28 && jj >= 0 && jj < 28) {
        const f32x4 v = *(const f32x4*)&x1[((size_t)b * 784 + ii * 28 + jj) * 576 + c];
        const f32x4 wv = *(const f32x4*)&wT[((dh + 1) * 3 + (dw + 1)) * 576 + c];
        acc += v * wv;
      }
    }
  }
  const f32x4 s = *(const f32x4*)&st[c];
  const f32x4 tt = *(const f32x4*)&st[576 + c];
  *(f32x4*)&x2[((size_t)b * 784 + pix) * 576 + c] = acc * s + tt;
}

// ---------- launch ----------
extern "C" void kernel_launch(void* const* d_in, const int* in_sizes, int n_in,
                              void* d_out, int out_size, void* d_ws, size_t ws_size,
                              hipStream_t stream) {
  (void)in_sizes; (void)n_in; (void)out_size; (void)ws_size;
  const float* x      = (const float*)d_in[0];
  const float* ln1g   = (const float*)d_in[1];
  const float* ln1b   = (const float*)d_in[2];
  const float* qkv_w  = (const float*)d_in[3];
  const float* qkv_b  = (const float*)d_in[4];
  const float* biases = (const float*)d_in[5];
  const float* proj_w = (const float*)d_in[6];
  const float* proj_b = (const float*)d_in[7];
  const float* conv_w = (const float*)d_in[8];
  const float* bng    = (const float*)d_in[9];
  const float* bnb    = (const float*)d_in[10];
  const float* bnm    = (const float*)d_in[11];
  const float* bnv    = (const float*)d_in[12];
  const float* ln2g   = (const float*)d_in[13];
  const float* ln2b   = (const float*)d_in[14];
  const float* fc1_w  = (const float*)d_in[15];
  const float* fc1_b  = (const float*)d_in[16];
  const float* fc2_w  = (const float*)d_in[17];
  const float* fc2_b  = (const float*)d_in[18];
  float* out = (float*)d_out;

  const int M = 25088;
  char* ws = (char*)d_ws;
  // Workspace:
  //   A [0, 57802752)           : x2 f32 (M x 576)
  //   B [57802752, +115605504)  : qkv bf16 (Mx1728) -> x1 f32 (Mx576) -> hm bf16 (Mx2304)
  //   C [173408256, +28901376)  : xn1 bf16 -> o bf16 -> xn2 bf16
  //   D [202309632, +7962624)   : transposed bf16 weights
  //   E [210272256, +25344)     : conv wT (9x576 f32) + st (2x576 f32)
  float* x2 = (float*)ws;
  char* regB = ws + 57802752;
  __hip_bfloat16* qkvb = (__hip_bfloat16*)regB;
  float*          x1   = (float*)regB;
  __hip_bfloat16* hm   = (__hip_bfloat16*)regB;
  char* regC = ws + 173408256;
  __hip_bfloat16* xn1  = (__hip_bfloat16*)regC;
  __hip_bfloat16* obuf = (__hip_bfloat16*)regC;
  __hip_bfloat16* xn2  = (__hip_bfloat16*)regC;
  char* regD = ws + 202309632;
  __hip_bfloat16* qkvT = (__hip_bfloat16*)regD;
  __hip_bfloat16* projT = (__hip_bfloat16*)(regD + 1990656);
  __hip_bfloat16* fc1T  = (__hip_bfloat16*)(regD + 1990656 + 663552);
  __hip_bfloat16* fc2T  = (__hip_bfloat16*)(regD + 1990656 + 663552 + 2654208);
  float* convT = (float*)(ws + 210272256);
  float* convST = convT + 9 * 576;

  // weight prep
  wt_kernel<<<dim3(1728 / 32, 576 / 32), 256, 0, stream>>>(qkv_w, qkvT, 576, 1728);
  wt_kernel<<<dim3(576 / 32, 576 / 32), 256, 0, stream>>>(proj_w, projT, 576, 576);
  wt_kernel<<<dim3(2304 / 32, 576 / 32), 256, 0, stream>>>(fc1_w, fc1T, 576, 2304);
  wt_kernel<<<dim3(576 / 32, 2304 / 32), 256, 0, stream>>>(fc2_w, fc2T, 2304, 576);
  convprep_kernel<<<(576 * 9 + 255) / 256, 256, 0, stream>>>(conv_w, bng, bnb, bnm, bnv, convT, convST);

  // 1. xn1 = LN1(x) bf16
  ln_bf16_kernel<<<M / 4, 256, 0, stream>>>(x, ln1g, ln1b, xn1);
  // 2. qkv = xn1 @ qkv_w + qkv_b (bf16 out)
  gemm_bt<0, __hip_bfloat16><<<27 * 196, 256, 0, stream>>>(xn1, qkvT, qkv_b, nullptr, qkvb, M, 1728, 576);
  // 3. attention (MFMA, 1 wave per window-head)
  attn_mfma_kernel<<<512 * 18, 64, 0, stream>>>(qkvb, biases, obuf);
  // 4. x1 = x + (o @ proj_w + proj_b)
  gemm_bt<1, float><<<9 * 196, 256, 0, stream>>>(obuf, projT, proj_b, x, x1, M, 576, 576);
  // 5. x2 = BN(dwconv(x1))
  conv_bn_kernel<<<(32 * 784 * 144 + 255) / 256, 256, 0, stream>>>(x1, convT, convST, x2);
  // 6. xn2 = LN2(x2) bf16
  ln_bf16_kernel<<<M / 4, 256, 0, stream>>>(x2, ln2g, ln2b, xn2);
  // 7. hm = gelu(xn2 @ fc1_w + fc1_b) bf16
  gemm_bt<2, __hip_bfloat16><<<36 * 196, 256, 0, stream>>>(xn2, fc1T, fc1_b, nullptr, hm, M, 2304, 576);
  // 8. out = x2 + (hm @ fc2_w + fc2_b)
  gemm_bt<1, float><<<9 * 196, 256, 0, stream>>>(hm, fc2T, fc2_b, x2, out, M, 576, 2304);
}

// Round 8
// 555.536 us; speedup vs baseline: 7.5546x; 1.0281x over previous
//
#include <hip/hip_runtime.h>
#include <hip/hip_bf16.h>

typedef __attribute__((ext_vector_type(8))) short bf16x8;
typedef __attribute__((ext_vector_type(4))) float f32x4;

static __device__ __forceinline__ void stf(float* p, size_t i, float v) { p[i] = v; }
static __device__ __forceinline__ void stf(__hip_bfloat16* p, size_t i, float v) { p[i] = __float2bfloat16(v); }

static __device__ __forceinline__ void gload_lds16(const void* g, void* l) {
  __builtin_amdgcn_global_load_lds((const __attribute__((address_space(1))) void*)g,
                                   (__attribute__((address_space(3))) void*)l, 16, 0, 0);
}

// ---------- weight transpose + bf16 convert: W[K][N] f32 -> WT[N][K] bf16 ----------
__global__ void wt_kernel(const float* __restrict__ W, __hip_bfloat16* __restrict__ WT, int K, int N) {
  __shared__ float tile[32][33];
  const int kb = blockIdx.y * 32, nb = blockIdx.x * 32;
  const int tx = threadIdx.x & 31, ty = threadIdx.x >> 5;
#pragma unroll
  for (int i = 0; i < 4; ++i)
    tile[ty + i * 8][tx] = W[(size_t)(kb + ty + i * 8) * N + nb + tx];
  __syncthreads();
#pragma unroll
  for (int i = 0; i < 4; ++i)
    WT[(size_t)(nb + ty + i * 8) * K + kb + tx] = __float2bfloat16(tile[tx][ty + i * 8]);
}

// ---------- conv prep: wT[tap][c] = w[c*9+tap]; s[c]=rsqrt(var+eps)*g; t[c]=b-mean*s ----------
__global__ void convprep_kernel(const float* __restrict__ w, const float* __restrict__ bng,
                                const float* __restrict__ bnb, const float* __restrict__ bnm,
                                const float* __restrict__ bnv, float* __restrict__ wT,
                                float* __restrict__ st) {
  const int i = blockIdx.x * 256 + threadIdx.x;
  if (i < 576 * 9) {
    const int t = i / 576, c = i - t * 576;
    wT[i] = w[c * 9 + t];
  }
  if (i < 576) {
    const float s = rsqrtf(bnv[i] + 1e-5f) * bng[i];
    st[i] = s;
    st[576 + i] = bnb[i] - bnm[i] * s;
  }
}

// ---------- fused LN -> bf16: one wave per 576-elem row ----------
__global__ void ln_bf16_kernel(const float* __restrict__ x, const float* __restrict__ g,
                               const float* __restrict__ b, __hip_bfloat16* __restrict__ y) {
  const int row = blockIdx.x * 4 + (threadIdx.x >> 6);
  const int lane = threadIdx.x & 63;
  const float* p = x + (size_t)row * 576;
  float vals[9];
  float s = 0.f, ss = 0.f;
#pragma unroll
  for (int i = 0; i < 9; ++i) {
    float v = p[lane + i * 64];
    vals[i] = v; s += v; ss += v * v;
  }
#pragma unroll
  for (int o = 32; o; o >>= 1) { s += __shfl_down(s, o); ss += __shfl_down(ss, o); }
  s = __shfl(s, 0); ss = __shfl(ss, 0);
  const float m = s * (1.f / 576.f);
  const float rstd = rsqrtf(ss * (1.f / 576.f) - m * m + 1e-5f);
  __hip_bfloat16* q = y + (size_t)row * 576;
#pragma unroll
  for (int i = 0; i < 9; ++i) {
    const int c = lane + i * 64;
    q[c] = __float2bfloat16((vals[i] - m) * rstd * g[c] + b[c]);
  }
}

// ---------- MFMA GEMM: C[M,N] = epi(A[M,K] @ BT[N,K]^T + bias) ----------
// tile BMxBN (128x192), BK=64, 4 waves (2x2), wave tile 64x96 (4x6 frags,
// 48 MFMA/K-step/wave), gload_lds + XOR swizzle, XCD-bijective panel-major grid.
// Intensity 77 F/staged-byte (vs 44 at 128x64) -> staging-BW-bound util ~33%.
// EPI: 0 none, 1 +res, 2 exact GELU
template <int BM, int BN, int EPI, typename TO>
__global__ __launch_bounds__(256, 2) void gemm_bt(
    const __hip_bfloat16* __restrict__ A, const __hip_bfloat16* __restrict__ BT,
    const float* __restrict__ bias, const float* __restrict__ res, TO* __restrict__ C,
    int M, int N, int K) {
  constexpr int WM = BM / 2, WN = BN / 2;
  constexpr int MI = WM / 16, NI = WN / 16;
  constexpr int AI = BM / 32, BI = BN / 32;  // stage iterations (256 thr, 16B each)
  __shared__ __hip_bfloat16 sA[2][BM * 64];
  __shared__ __hip_bfloat16 sB[2][BN * 64];
  const int t = threadIdx.x;
  const int lane = t & 63;
  const int w = t >> 6;
  // bijective XCD swizzle (m204)
  const int nwg = gridDim.x;
  const int qq = nwg >> 3, r = nwg & 7;
  const int xcd = blockIdx.x & 7, lidx = blockIdx.x >> 3;
  const int wgid = (xcd < r ? xcd * (qq + 1) : r * (qq + 1) + (xcd - r) * qq) + lidx;
  const int nx = N / BN;
  const int bm = (wgid / nx) * BM, bn = (wgid % nx) * BN;
  const int wm = (w >> 1) * WM, wn = (w & 1) * WN;
  const int l15 = lane & 15, l4 = lane >> 4;

  f32x4 acc[MI][NI];
#pragma unroll
  for (int mi = 0; mi < MI; ++mi)
#pragma unroll
    for (int ni = 0; ni < NI; ++ni) acc[mi][ni] = (f32x4){0.f, 0.f, 0.f, 0.f};

  const int wave_base = t & ~63;

  auto stage = [&](int buf, int k0) {
#pragma unroll
    for (int i = 0; i < AI; ++i) {
      const int slot = i * 256 + t;
      const int row = slot >> 3, kst = slot & 7;
      const int ksrc = kst ^ (row & 7);
      const __hip_bfloat16* g = A + (size_t)(bm + row) * K + k0 + ksrc * 8;
      gload_lds16(g, sA[buf] + (i * 256 + wave_base) * 8);
    }
#pragma unroll
    for (int i = 0; i < BI; ++i) {
      const int slot = i * 256 + t;
      const int row = slot >> 3, kst = slot & 7;
      const int ksrc = kst ^ (row & 7);
      const __hip_bfloat16* g = BT + (size_t)(bn + row) * K + k0 + ksrc * 8;
      gload_lds16(g, sB[buf] + (i * 256 + wave_base) * 8);
    }
  };

  auto compute = [&](int buf) {
    const __hip_bfloat16* pA = sA[buf];
    const __hip_bfloat16* pB = sB[buf];
#pragma unroll
    for (int kb = 0; kb < 2; ++kb) {
      bf16x8 a[MI], b[NI];
      const int kblk = kb * 4 + l4;
#pragma unroll
      for (int mi = 0; mi < MI; ++mi) {
        const int row = wm + mi * 16 + l15;
        a[mi] = *(const bf16x8*)(pA + row * 64 + ((kblk ^ (row & 7)) * 8));
      }
#pragma unroll
      for (int ni = 0; ni < NI; ++ni) {
        const int row = wn + ni * 16 + l15;
        b[ni] = *(const bf16x8*)(pB + row * 64 + ((kblk ^ (row & 7)) * 8));
      }
#pragma unroll
      for (int mi = 0; mi < MI; ++mi)
#pragma unroll
        for (int ni = 0; ni < NI; ++ni)
          acc[mi][ni] = __builtin_amdgcn_mfma_f32_16x16x32_bf16(a[mi], b[ni], acc[mi][ni], 0, 0, 0);
    }
  };

  const int nt = K >> 6;
  stage(0, 0);
  __syncthreads();
  int cur = 0;
  for (int tt = 0; tt < nt - 1; ++tt) {
    stage(cur ^ 1, (tt + 1) << 6);
    compute(cur);
    __syncthreads();
    cur ^= 1;
  }
  compute(cur);

#pragma unroll
  for (int mi = 0; mi < MI; ++mi) {
    const int mrow = bm + wm + mi * 16 + l4 * 4;
#pragma unroll
    for (int ni = 0; ni < NI; ++ni) {
      const int col = bn + wn + ni * 16 + l15;
      const float bv = bias[col];
#pragma unroll
      for (int r2 = 0; r2 < 4; ++r2) {
        const size_t idx = (size_t)(mrow + r2) * N + col;
        float v = acc[mi][ni][r2] + bv;
        if (EPI == 1) v += res[idx];
        if (EPI == 2) v = 0.5f * v * (1.0f + erff(v * 0.70710678118654752f));
        stf(C, idx, v);
      }
    }
  }
}

// ---------- MFMA windowed attention: 1 wave per (window, head) ----------
__global__ __launch_bounds__(64) void attn_mfma_kernel(
    const __hip_bfloat16* __restrict__ qkv, const float* __restrict__ biases,
    __hip_bfloat16* __restrict__ o) {
  __shared__ __hip_bfloat16 sQK[2][64][40];
  __shared__ __hip_bfloat16 sVT[32][72];
  __hip_bfloat16 (*sP)[72] = (__hip_bfloat16(*)[72])(&sQK[0][0][0]);

  const int wid  = blockIdx.x / 18;
  const int head = blockIdx.x - wid * 18;
  const int b  = wid >> 4;
  const int wi = wid & 15;
  const int wh = wi >> 2, wwc = wi & 3;
  const int lane = threadIdx.x;
  const int l15 = lane & 15, l4 = lane >> 4;

  {
    const __hip_bfloat16* basep = qkv + (size_t)head * 96;
    for (int idx = lane; idx < 49 * 12; idx += 64) {
      const int tkn = idx / 12, part = idx - tkn * 12;
      const int r = tkn / 7, c = tkn - r * 7;
      const size_t row = (size_t)b * 784 + (size_t)((wh * 7 + r) * 28 + wwc * 7 + c);
      bf16x8 v = *(const bf16x8*)(basep + row * 1728 + part * 8);
      if (part < 4)      *(bf16x8*)&sQK[0][tkn][part * 8] = v;
      else if (part < 8) *(bf16x8*)&sQK[1][tkn][(part - 4) * 8] = v;
      else {
        const int d0 = (part - 8) * 8;
        const short* sv = (const short*)&v;
#pragma unroll
        for (int e = 0; e < 8; ++e)
          sVT[d0 + e][tkn] = *(const __hip_bfloat16*)&sv[e];
      }
    }
    for (int idx = lane; idx < 32 * 15; idx += 64) {
      const int d = idx / 15, tt = 49 + (idx - d * 15);
      sVT[d][tt] = __float2bfloat16(0.0f);
    }
  }
  __syncthreads();

  f32x4 acc[4][4];
#pragma unroll
  for (int mi = 0; mi < 4; ++mi)
#pragma unroll
    for (int ni = 0; ni < 4; ++ni) acc[mi][ni] = (f32x4){0.f, 0.f, 0.f, 0.f};
  {
    bf16x8 aq[4], bk[4];
#pragma unroll
    for (int mi = 0; mi < 4; ++mi) aq[mi] = *(const bf16x8*)&sQK[0][mi * 16 + l15][l4 * 8];
#pragma unroll
    for (int ni = 0; ni < 4; ++ni) bk[ni] = *(const bf16x8*)&sQK[1][ni * 16 + l15][l4 * 8];
#pragma unroll
    for (int mi = 0; mi < 4; ++mi)
#pragma unroll
      for (int ni = 0; ni < 4; ++ni)
        acc[mi][ni] = __builtin_amdgcn_mfma_f32_16x16x32_bf16(aq[mi], bk[ni], acc[mi][ni], 0, 0, 0);
  }
  __syncthreads();

  const float scale = 0.17677669529663687f;
  const float* btab = biases + head * 49;
#pragma unroll
  for (int mi = 0; mi < 4; ++mi) {
#pragma unroll
    for (int rr = 0; rr < 4; ++rr) {
      const int i = mi * 16 + l4 * 4 + rr;
      const int ic = i < 49 ? i : 0;
      const int ri = ic / 7, ci = ic - ri * 7;
      float s[4];
#pragma unroll
      for (int ni = 0; ni < 4; ++ni) {
        const int j = ni * 16 + l15;
        if (j < 49) {
          const int rj = j / 7, cj = j - rj * 7;
          s[ni] = acc[mi][ni][rr] * scale + btab[__builtin_abs(ri - rj) * 7 + __builtin_abs(ci - cj)];
        } else {
          s[ni] = -1e30f;
        }
      }
      float m = fmaxf(fmaxf(s[0], s[1]), fmaxf(s[2], s[3]));
#pragma unroll
      for (int d = 1; d < 16; d <<= 1) m = fmaxf(m, __shfl_xor(m, d));
      float sum = 0.f;
#pragma unroll
      for (int ni = 0; ni < 4; ++ni) { s[ni] = __expf(s[ni] - m); sum += s[ni]; }
#pragma unroll
      for (int d = 1; d < 16; d <<= 1) sum += __shfl_xor(sum, d);
      const float inv = 1.0f / sum;
#pragma unroll
      for (int ni = 0; ni < 4; ++ni)
        sP[i][ni * 16 + l15] = __float2bfloat16(s[ni] * inv);
    }
  }
  __syncthreads();

  f32x4 oacc[4][2];
#pragma unroll
  for (int mi = 0; mi < 4; ++mi)
#pragma unroll
    for (int ni = 0; ni < 2; ++ni) oacc[mi][ni] = (f32x4){0.f, 0.f, 0.f, 0.f};
#pragma unroll
  for (int kb = 0; kb < 2; ++kb) {
    bf16x8 ap[4], bv[2];
#pragma unroll
    for (int mi = 0; mi < 4; ++mi) ap[mi] = *(const bf16x8*)&sP[mi * 16 + l15][kb * 32 + l4 * 8];
#pragma unroll
    for (int ni = 0; ni < 2; ++ni) bv[ni] = *(const bf16x8*)&sVT[ni * 16 + l15][kb * 32 + l4 * 8];
#pragma unroll
    for (int mi = 0; mi < 4; ++mi)
#pragma unroll
      for (int ni = 0; ni < 2; ++ni)
        oacc[mi][ni] = __builtin_amdgcn_mfma_f32_16x16x32_bf16(ap[mi], bv[ni], oacc[mi][ni], 0, 0, 0);
  }

#pragma unroll
  for (int mi = 0; mi < 4; ++mi) {
#pragma unroll
    for (int rr = 0; rr < 4; ++rr) {
      const int i = mi * 16 + l4 * 4 + rr;
      if (i < 49) {
        const int r = i / 7, c = i - r * 7;
        const size_t grow = (size_t)b * 784 + (size_t)((wh * 7 + r) * 28 + wwc * 7 + c);
#pragma unroll
        for (int ni = 0; ni < 2; ++ni)
          o[grow * 576 + head * 32 + ni * 16 + l15] = __float2bfloat16(oacc[mi][ni][rr]);
      }
    }
  }
}

// ---------- depthwise 3x3 conv + folded BN, float4 over channels ----------
__global__ void conv_bn_kernel(const float* __restrict__ x1, const float* __restrict__ wT,
                               const float* __restrict__ st, float* __restrict__ x2) {
  const size_t total = (size_t)32 * 784 * 144;
  const size_t idx = (size_t)blockIdx.x * 256 + threadIdx.x;
  if (idx >= total) return;
  const int c4 = (int)(idx % 144);
  const size_t p = idx / 144;
  const int pix = (int)(p % 784);
  const int b = (int)(p / 784);
  const int i = pix / 28, j = pix - (pix / 28) * 28;
  const int c = c4 * 4;
  f32x4 acc = (f32x4){0.f, 0.f, 0.f, 0.f};
#pragma unroll
  for (int dh = -1; dh <= 1; ++dh) {
#pragma unroll
    for (int dw = -1; dw <= 1; ++dw) {
      const int ii = i + dh, jj = j + dw;
      if (ii >= 0 && ii < 28 && jj >= 0 && jj < 28) {
        const f32x4 v = *(const f32x4*)&x1[((size_t)b * 784 + ii * 28 + jj) * 576 + c];
        const f32x4 wv = *(const f32x4*)&wT[((dh + 1) * 3 + (dw + 1)) * 576 + c];
        acc += v * wv;
      }
    }
  }
  const f32x4 s = *(const f32x4*)&st[c];
  const f32x4 tt = *(const f32x4*)&st[576 + c];
  *(f32x4*)&x2[((size_t)b * 784 + pix) * 576 + c] = acc * s + tt;
}

// ---------- launch ----------
extern "C" void kernel_launch(void* const* d_in, const int* in_sizes, int n_in,
                              void* d_out, int out_size, void* d_ws, size_t ws_size,
                              hipStream_t stream) {
  (void)in_sizes; (void)n_in; (void)out_size; (void)ws_size;
  const float* x      = (const float*)d_in[0];
  const float* ln1g   = (const float*)d_in[1];
  const float* ln1b   = (const float*)d_in[2];
  const float* qkv_w  = (const float*)d_in[3];
  const float* qkv_b  = (const float*)d_in[4];
  const float* biases = (const float*)d_in[5];
  const float* proj_w = (const float*)d_in[6];
  const float* proj_b = (const float*)d_in[7];
  const float* conv_w = (const float*)d_in[8];
  const float* bng    = (const float*)d_in[9];
  const float* bnb    = (const float*)d_in[10];
  const float* bnm    = (const float*)d_in[11];
  const float* bnv    = (const float*)d_in[12];
  const float* ln2g   = (const float*)d_in[13];
  const float* ln2b   = (const float*)d_in[14];
  const float* fc1_w  = (const float*)d_in[15];
  const float* fc1_b  = (const float*)d_in[16];
  const float* fc2_w  = (const float*)d_in[17];
  const float* fc2_b  = (const float*)d_in[18];
  float* out = (float*)d_out;

  const int M = 25088;
  char* ws = (char*)d_ws;
  // Workspace:
  //   A [0, 57802752)           : x2 f32 (M x 576)
  //   B [57802752, +115605504)  : qkv bf16 (Mx1728) -> x1 f32 (Mx576) -> hm bf16 (Mx2304)
  //   C [173408256, +28901376)  : xn1 bf16 -> o bf16 -> xn2 bf16
  //   D [202309632, +7962624)   : transposed bf16 weights
  //   E [210272256, +25344)     : conv wT (9x576 f32) + st (2x576 f32)
  float* x2 = (float*)ws;
  char* regB = ws + 57802752;
  __hip_bfloat16* qkvb = (__hip_bfloat16*)regB;
  float*          x1   = (float*)regB;
  __hip_bfloat16* hm   = (__hip_bfloat16*)regB;
  char* regC = ws + 173408256;
  __hip_bfloat16* xn1  = (__hip_bfloat16*)regC;
  __hip_bfloat16* obuf = (__hip_bfloat16*)regC;
  __hip_bfloat16* xn2  = (__hip_bfloat16*)regC;
  char* regD = ws + 202309632;
  __hip_bfloat16* qkvT = (__hip_bfloat16*)regD;
  __hip_bfloat16* projT = (__hip_bfloat16*)(regD + 1990656);
  __hip_bfloat16* fc1T  = (__hip_bfloat16*)(regD + 1990656 + 663552);
  __hip_bfloat16* fc2T  = (__hip_bfloat16*)(regD + 1990656 + 663552 + 2654208);
  float* convT = (float*)(ws + 210272256);
  float* convST = convT + 9 * 576;

  // weight prep
  wt_kernel<<<dim3(1728 / 32, 576 / 32), 256, 0, stream>>>(qkv_w, qkvT, 576, 1728);
  wt_kernel<<<dim3(576 / 32, 576 / 32), 256, 0, stream>>>(proj_w, projT, 576, 576);
  wt_kernel<<<dim3(2304 / 32, 576 / 32), 256, 0, stream>>>(fc1_w, fc1T, 576, 2304);
  wt_kernel<<<dim3(576 / 32, 2304 / 32), 256, 0, stream>>>(fc2_w, fc2T, 2304, 576);
  convprep_kernel<<<(576 * 9 + 255) / 256, 256, 0, stream>>>(conv_w, bng, bnb, bnm, bnv, convT, convST);

  // 1. xn1 = LN1(x) bf16
  ln_bf16_kernel<<<M / 4, 256, 0, stream>>>(x, ln1g, ln1b, xn1);
  // 2. qkv = xn1 @ qkv_w + qkv_b (bf16 out); N=1728 = 9*192
  gemm_bt<128, 192, 0, __hip_bfloat16><<<9 * 196, 256, 0, stream>>>(xn1, qkvT, qkv_b, nullptr, qkvb, M, 1728, 576);
  // 3. attention (MFMA, 1 wave per window-head)
  attn_mfma_kernel<<<512 * 18, 64, 0, stream>>>(qkvb, biases, obuf);
  // 4. x1 = x + (o @ proj_w + proj_b); N=576 = 3*192
  gemm_bt<128, 192, 1, float><<<3 * 196, 256, 0, stream>>>(obuf, projT, proj_b, x, x1, M, 576, 576);
  // 5. x2 = BN(dwconv(x1))
  conv_bn_kernel<<<(32 * 784 * 144 + 255) / 256, 256, 0, stream>>>(x1, convT, convST, x2);
  // 6. xn2 = LN2(x2) bf16
  ln_bf16_kernel<<<M / 4, 256, 0, stream>>>(x2, ln2g, ln2b, xn2);
  // 7. hm = gelu(xn2 @ fc1_w + fc1_b) bf16; N=2304 = 12*192
  gemm_bt<128, 192, 2, __hip_bfloat16><<<12 * 196, 256, 0, stream>>>(xn2, fc1T, fc1_b, nullptr, hm, M, 2304, 576);
  // 8. out = x2 + (hm @ fc2_w + fc2_b); K=2304
  gemm_bt<128, 192, 1, float><<<3 * 196, 256, 0, stream>>>(hm, fc2T, fc2_b, x2, out, M, 576, 2304);
}